// Round 12
// baseline (349.953 us; speedup 1.0000x reference)
//
#include <hip/hip_runtime.h>
#include <hip/hip_bf16.h>

// Shapes
#define B_   32
#define L_   2048
#define D_   128
#define NL_  3
#define KVB  64
#define NKT  (L_ / KVB)         // 32

typedef __attribute__((ext_vector_type(8))) short short8;
typedef __attribute__((ext_vector_type(4))) float f32x4;
typedef __attribute__((ext_vector_type(16))) float f32x16;

__device__ __forceinline__ short f2bf(float f) {
    unsigned u = __builtin_bit_cast(unsigned, f);
    u += 0x7fffu + ((u >> 16) & 1u);          // RNE
    return (short)(u >> 16);
}
// v_exp_f32 computes 2^x
__device__ __forceinline__ float exp2g(float x) {
    float r; asm("v_exp_f32 %0, %1" : "=v"(r) : "v"(x)); return r;
}
// pack two f32 -> 2x bf16 in one u32 (low=a, high=b), RNE
__device__ __forceinline__ unsigned cvtpk(float a, float b) {
    unsigned r; asm("v_cvt_pk_bf16_f32 %0, %1, %2" : "=v"(r) : "v"(a), "v"(b)); return r;
}
// swap halves across lane<32 / lane>=32 (m214 T12 pattern)
__device__ __forceinline__ void plswap(unsigned& a, unsigned& b) {
    asm volatile("v_permlane32_swap_b32 %0, %1" : "+v"(a), "+v"(b));
}

// async global -> LDS, 16 bytes per lane (dest must be linear: base + lane*16)
__device__ __forceinline__ void gll16(const void* g, void* l) {
    __builtin_amdgcn_global_load_lds(
        (__attribute__((address_space(1))) void*)(g),
        (__attribute__((address_space(3))) void*)(l), 16, 0, 0);
}

// Fragment-order global layouts (16B granule per lane):
//  Q/K: addr = b*512K + blk32*8K + dst*1K + lane*16
//  Vt:  addr = b*512K + kt*16K + k16*4K + d2*1K + lane*16

// ---------------------------------------------------------------- form x
__global__ __launch_bounds__(256) void k_form_x(const float* __restrict__ g,
                                                const float* __restrict__ emb,
                                                short* __restrict__ X) {
    int tid = blockIdx.x * 256 + threadIdx.x;   // one thread = 8 elements
    int bl  = tid >> 4;
    int d8  = (tid & 15) << 3;
    int l   = bl & (L_ - 1);
    float gv = g[bl];
    const float4* e = reinterpret_cast<const float4*>(emb + (size_t)l * D_ + d8);
    float4 a = e[0], b = e[1];
    short8 r;
    r[0]=f2bf(a.x*gv); r[1]=f2bf(a.y*gv); r[2]=f2bf(a.z*gv); r[3]=f2bf(a.w*gv);
    r[4]=f2bf(b.x*gv); r[5]=f2bf(b.y*gv); r[6]=f2bf(b.z*gv); r[7]=f2bf(b.w*gv);
    *reinterpret_cast<short8*>(X + (size_t)tid * 8) = r;
}

// ---------------------------------------------------------------- weight convert
__global__ __launch_bounds__(256) void k_convw(const float* __restrict__ qw,
                                               const float* __restrict__ kw,
                                               const float* __restrict__ vw,
                                               short* __restrict__ Wbf) {
    const float* src = (blockIdx.y == 0) ? qw : (blockIdx.y == 1) ? kw : vw;
    int tid = blockIdx.x * 256 + threadIdx.x;   // 0..6143
    int layer = tid >> 11;
    int i = tid & 2047;
    int Lb = i * 16;
    int row = Lb >> 8, c = (Lb & 255) ^ ((row & 7) << 4);
    const float4* p = reinterpret_cast<const float4*>(src + (size_t)layer * 16384 + row * 128 + (c >> 1));
    float4 a = p[0], b = p[1];
    short8 s;
    s[0]=f2bf(a.x); s[1]=f2bf(a.y); s[2]=f2bf(a.z); s[3]=f2bf(a.w);
    s[4]=f2bf(b.x); s[5]=f2bf(b.y); s[6]=f2bf(b.z); s[7]=f2bf(b.w);
    size_t off = ((size_t)layer * 3 + blockIdx.y) * 16384;
    *reinterpret_cast<short8*>(Wbf + off + (size_t)i * 8) = s;
}

// ---------------------------------------------------------------- fused QKV GEMM
// ONE launch: 512 blocks (XCD-grouped, matches attn's batch<->XCD map).
// X staged once; W (32KB, L2-hot) re-staged per mat between barriers.
// Outputs in FRAGMENT ORDER. Q pre-scaled by log2(e).
__global__ __launch_bounds__(256, 2) void k_qkv3(const short* __restrict__ X,
    const short* __restrict__ Wl,
    const float* __restrict__ bq, const float* __restrict__ bk, const float* __restrict__ bv,
    short* __restrict__ Qf, short* __restrict__ Kf, short* __restrict__ Vf) {
    __shared__ short xs[128 * 128];
    __shared__ short wsh[128 * 128];
    const int t = threadIdx.x;
    int flat = blockIdx.x, xcd = flat & 7, idx = flat >> 3;
    int rblk = xcd * 64 + idx;                 // XCD0 -> rows 0..8191 = batches 0..3
    const size_t rowbase = (size_t)rblk * 128;

    const char* Xg = reinterpret_cast<const char*>(X) + rowbase * 256;
#pragma unroll
    for (int p = 0; p < 8; p++) {
        int Lb = (p * 256 + t) * 16;
        int row = Lb >> 8, c = Lb & 255;
        gll16(Xg + (size_t)row * 256 + (c ^ ((row & 7) << 4)),
              reinterpret_cast<char*>(xs) + Lb);
    }
#pragma unroll
    for (int p = 0; p < 8; p++) {             // W for mat 0
        int Lb = (p * 256 + t) * 16;
        gll16(reinterpret_cast<const char*>(Wl) + Lb,
              reinterpret_cast<char*>(wsh) + Lb);
    }
    __syncthreads();

    const int wave = t >> 6, lane = t & 63, g = lane >> 4, ln = lane & 15;
    const int bb2 = (int)(rowbase >> 11);      // batch
    const int l0  = (int)(rowbase & (L_ - 1)); // row within batch

#pragma unroll
    for (int mat = 0; mat < 3; mat++) {
        if (mat > 0) {
            __syncthreads();                   // all waves done reading wsh (mat-1)
#pragma unroll
            for (int p = 0; p < 8; p++) {
                int Lb = (p * 256 + t) * 16;
                gll16(reinterpret_cast<const char*>(Wl + mat * 16384) + Lb,
                      reinterpret_cast<char*>(wsh) + Lb);
            }
            __syncthreads();                   // vmcnt(0) drained before barrier
        }
        const float* bias = (mat == 0) ? bq : (mat == 1) ? bk : bv;
        f32x4 acc[2][8];
#pragma unroll
        for (int mi = 0; mi < 2; mi++)
#pragma unroll
            for (int ni = 0; ni < 8; ni++) acc[mi][ni] = f32x4{0.f, 0.f, 0.f, 0.f};

        if (mat < 2) {
            // A = W (rows e), B = X (rows l) -> C[e][l]
#pragma unroll
            for (int kk = 0; kk < 4; kk++) {
                short8 aW[2];
#pragma unroll
                for (int mi = 0; mi < 2; mi++) {
                    int row = wave * 32 + mi * 16 + ln;
                    int byte = (row * 256 + kk * 64 + g * 16) ^ ((row & 7) << 4);
                    aW[mi] = *reinterpret_cast<const short8*>(reinterpret_cast<const char*>(wsh) + byte);
                }
#pragma unroll
                for (int ni = 0; ni < 8; ni++) {
                    int row = ni * 16 + ln;
                    int byte = (row * 256 + kk * 64 + g * 16) ^ ((row & 7) << 4);
                    short8 bX = *reinterpret_cast<const short8*>(reinterpret_cast<const char*>(xs) + byte);
                    acc[0][ni] = __builtin_amdgcn_mfma_f32_16x16x32_bf16(aW[0], bX, acc[0][ni], 0, 0, 0);
                    acc[1][ni] = __builtin_amdgcn_mfma_f32_16x16x32_bf16(aW[1], bX, acc[1][ni], 0, 0, 0);
                }
            }
            const float qscale = (mat == 0) ? 1.4426950408889634f : 1.0f;
            char* oc = reinterpret_cast<char*>((mat == 0) ? Qf : Kf) + ((size_t)bb2 << 19);
            int lidx_hi = ((g >> 1) & 1) << 5;
#pragma unroll
            for (int mi = 0; mi < 2; mi++) {
                int e0 = wave * 32 + mi * 16 + g * 4;
                int dst = wave * 2 + mi;
                float4 b4 = *reinterpret_cast<const float4*>(bias + e0);
#pragma unroll
                for (int ni = 0; ni < 8; ni++) {
                    unsigned lo = (unsigned short)f2bf((acc[mi][ni][0] + b4.x) * qscale)
                                | ((unsigned)(unsigned short)f2bf((acc[mi][ni][1] + b4.y) * qscale) << 16);
                    unsigned hi2 = (unsigned short)f2bf((acc[mi][ni][2] + b4.z) * qscale)
                                | ((unsigned)(unsigned short)f2bf((acc[mi][ni][3] + b4.w) * qscale) << 16);
                    int blk32 = (l0 >> 5) + (ni >> 1);
                    int l31 = ((ni & 1) << 4) + ln;
                    size_t off = ((size_t)(blk32 * 8 + dst) << 10)
                               + ((lidx_hi + l31) << 4) + ((g & 1) << 3);
                    int2 pk; pk.x = (int)lo; pk.y = (int)hi2;
                    *reinterpret_cast<int2*>(oc + off) = pk;
                }
            }
        } else {
            // V: A = X (rows l), B = W (rows e) -> C[l][e]
#pragma unroll
            for (int kk = 0; kk < 4; kk++) {
                short8 aX[2];
#pragma unroll
                for (int mi = 0; mi < 2; mi++) {
                    int row = wave * 32 + mi * 16 + ln;
                    int byte = (row * 256 + kk * 64 + g * 16) ^ ((row & 7) << 4);
                    aX[mi] = *reinterpret_cast<const short8*>(reinterpret_cast<const char*>(xs) + byte);
                }
#pragma unroll
                for (int ni = 0; ni < 8; ni++) {
                    int row = ni * 16 + ln;
                    int byte = (row * 256 + kk * 64 + g * 16) ^ ((row & 7) << 4);
                    short8 bW = *reinterpret_cast<const short8*>(reinterpret_cast<const char*>(wsh) + byte);
                    acc[0][ni] = __builtin_amdgcn_mfma_f32_16x16x32_bf16(aX[0], bW, acc[0][ni], 0, 0, 0);
                    acc[1][ni] = __builtin_amdgcn_mfma_f32_16x16x32_bf16(aX[1], bW, acc[1][ni], 0, 0, 0);
                }
            }
            char* oc = reinterpret_cast<char*>(Vf) + ((size_t)bb2 << 19);
#pragma unroll
            for (int ni = 0; ni < 8; ni++) {
                int d = ni * 16 + ln;
                float bvv = bias[d];
                int d2 = d >> 5, d31 = d & 31;
#pragma unroll
                for (int mi = 0; mi < 2; mi++) {
                    unsigned lo = (unsigned short)f2bf(acc[mi][ni][0] + bvv)
                                | ((unsigned)(unsigned short)f2bf(acc[mi][ni][1] + bvv) << 16);
                    unsigned hi2 = (unsigned short)f2bf(acc[mi][ni][2] + bvv)
                                | ((unsigned)(unsigned short)f2bf(acc[mi][ni][3] + bvv) << 16);
                    int lglob = l0 + wave * 32 + mi * 16 + g * 4;
                    int kt = lglob >> 6, k16 = (lglob >> 4) & 3, lhi = (lglob >> 3) & 1;
                    size_t off = ((size_t)kt << 14) + (k16 << 12) + (d2 << 10)
                               + ((lhi * 32 + d31) << 4) + ((g & 1) << 3);
                    int2 pk; pk.x = (int)lo; pk.y = (int)hi2;
                    *reinterpret_cast<int2*>(oc + off) = pk;
                }
            }
        }
    }
}

// ---------------------------------------------------------------- flash attention
// T15 pipeline + R12 ILP surgery: QK split into 4 independent 4-deep MFMA chains
// (s0a+s0b, s1a+s1b) seeded from a hoisted zero vector (no per-iter zero-movs);
// lsum tree-reduced (depth 6 vs 64). V triple-buffered, K double-buffered,
// K-before-V issue queue, vmcnt(12) per iter.
__global__ __launch_bounds__(256, 2) void k_attn(const short* __restrict__ Qf,
                                                 const short* __restrict__ Kf,
                                                 const short* __restrict__ Vf,
                                                 short* __restrict__ Xo,
                                                 const float* __restrict__ rw,
                                                 const float* __restrict__ rb,
                                                 float* __restrict__ out,
                                                 int fuse) {
    __shared__ short Ks[2][KVB * 128];    // 2 x 16 KB, fragment order
    __shared__ short Vts[3][128 * KVB];   // 3 x 16 KB, fragment order
    const int t = threadIdx.x, w = t >> 6, lane = t & 63;
    const int hi = lane >> 5, c5 = lane & 31;
    int flat = blockIdx.x;
    int xcd = flat & 7, idx = flat >> 3;
    int b = xcd * 4 + (idx >> 4), qt = idx & 15;
    const size_t qbase = (size_t)b * L_ + qt * 128;

    // Q fragments -> registers (contiguous 1KB per load)
    const char* Qg = reinterpret_cast<const char*>(Qf) + ((size_t)b << 19);
    short8 qf[8];
#pragma unroll
    for (int dst = 0; dst < 8; dst++)
        qf[dst] = *reinterpret_cast<const short8*>(
            Qg + (((size_t)(qt * 4 + w) * 8 + dst) << 10) + lane * 16);
    __builtin_amdgcn_sched_barrier(0);    // pin Q loads before staging (vmcnt accounting)

    const char* Kg = reinterpret_cast<const char*>(Kf) + ((size_t)b << 19);
    const char* Vg = reinterpret_cast<const char*>(Vf) + ((size_t)b << 19);

    auto stageK = [&](int kt) {
#pragma unroll
        for (int p = 0; p < 4; p++) {
            int Lb = (p * 256 + t) * 16;
            gll16(Kg + ((size_t)kt << 14) + Lb, reinterpret_cast<char*>(Ks[kt & 1]) + Lb);
        }
    };
    auto stageV = [&](int kt) {
#pragma unroll
        for (int p = 0; p < 4; p++) {
            int Lb = (p * 256 + t) * 16;
            gll16(Vg + ((size_t)kt << 14) + Lb, reinterpret_cast<char*>(Vts[kt % 3]) + Lb);
        }
    };

    // issue queue: K0 K1 V0 V1 | K2 V2 | K3 V3 | ...  (K-before-V prefix property)
    stageK(0); stageK(1); stageV(0); stageV(1);

    f32x16 z16;                           // hoisted zero C-operand (loop-invariant)
#pragma unroll
    for (int r = 0; r < 16; r++) z16[r] = 0.f;

    f32x16 o[4];
#pragma unroll
    for (int d2 = 0; d2 < 4; d2++) o[d2] = z16;
    float lsum = 0.f;
    short8 pa[4];                         // P fragments of the PREVIOUS iter

    auto softmax = [&](const f32x16& s0, const f32x16& s1) {
        float e0[16], e1[16];
#pragma unroll
        for (int r = 0; r < 16; r++) { e0[r] = exp2g(s0[r]); e1[r] = exp2g(s1[r]); }
        // tree-reduce: 16 independent adds, then depth-4 tree (chain depth ~6)
        float tr[16];
#pragma unroll
        for (int r = 0; r < 16; r++) tr[r] = e0[r] + e1[r];
#pragma unroll
        for (int st = 8; st > 0; st >>= 1)
#pragma unroll
            for (int r = 0; r < st; r++) tr[r] += tr[r + st];
        lsum += tr[0];
#pragma unroll
        for (int kt16 = 0; kt16 < 4; kt16++) {
            const float* e = (kt16 < 2) ? e0 : e1;
            int rb2 = (kt16 & 1) * 8;
            unsigned w01 = cvtpk(e[rb2 + 0], e[rb2 + 1]);
            unsigned w23 = cvtpk(e[rb2 + 2], e[rb2 + 3]);
            unsigned w45 = cvtpk(e[rb2 + 4], e[rb2 + 5]);
            unsigned w67 = cvtpk(e[rb2 + 6], e[rb2 + 7]);
            plswap(w01, w45);
            plswap(w23, w67);
            uint4 fr; fr.x = w01; fr.y = w23; fr.z = w45; fr.w = w67;
            pa[kt16] = __builtin_bit_cast(short8, fr);
        }
    };
    auto qk = [&](int kt, f32x16& s0, f32x16& s1) {
        const char* Kb8 = reinterpret_cast<const char*>(Ks[kt & 1]) + lane * 16;
        __builtin_amdgcn_s_setprio(1);
        // four independent 4-deep chains (s0a,s0b,s1a,s1b), seeded with z16
        short8 kA0 = *reinterpret_cast<const short8*>(Kb8);
        short8 kB0 = *reinterpret_cast<const short8*>(Kb8 + 8192);
        short8 kA4 = *reinterpret_cast<const short8*>(Kb8 + 4 * 1024);
        short8 kB4 = *reinterpret_cast<const short8*>(Kb8 + 8192 + 4 * 1024);
        f32x16 s0a = __builtin_amdgcn_mfma_f32_32x32x16_bf16(kA0, qf[0], z16, 0, 0, 0);
        f32x16 s1a = __builtin_amdgcn_mfma_f32_32x32x16_bf16(kB0, qf[0], z16, 0, 0, 0);
        f32x16 s0b = __builtin_amdgcn_mfma_f32_32x32x16_bf16(kA4, qf[4], z16, 0, 0, 0);
        f32x16 s1b = __builtin_amdgcn_mfma_f32_32x32x16_bf16(kB4, qf[4], z16, 0, 0, 0);
#pragma unroll
        for (int dst = 1; dst < 4; dst++) {
            short8 a0 = *reinterpret_cast<const short8*>(Kb8 + dst * 1024);
            short8 b0 = *reinterpret_cast<const short8*>(Kb8 + 8192 + dst * 1024);
            short8 a4 = *reinterpret_cast<const short8*>(Kb8 + (dst + 4) * 1024);
            short8 b4 = *reinterpret_cast<const short8*>(Kb8 + 8192 + (dst + 4) * 1024);
            s0a = __builtin_amdgcn_mfma_f32_32x32x16_bf16(a0, qf[dst], s0a, 0, 0, 0);
            s1a = __builtin_amdgcn_mfma_f32_32x32x16_bf16(b0, qf[dst], s1a, 0, 0, 0);
            s0b = __builtin_amdgcn_mfma_f32_32x32x16_bf16(a4, qf[dst + 4], s0b, 0, 0, 0);
            s1b = __builtin_amdgcn_mfma_f32_32x32x16_bf16(b4, qf[dst + 4], s1b, 0, 0, 0);
        }
        __builtin_amdgcn_s_setprio(0);
#pragma unroll
        for (int r = 0; r < 16; r++) { s0[r] = s0a[r] + s0b[r]; s1[r] = s1a[r] + s1b[r]; }
    };
    auto pv = [&](int kt) {               // O += P(kt).V(kt), pa holds P(kt)
        const char* Vb8 = reinterpret_cast<const char*>(Vts[kt % 3]) + lane * 16;
        __builtin_amdgcn_s_setprio(1);
#pragma unroll
        for (int kt16 = 0; kt16 < 4; kt16++) {
#pragma unroll
            for (int d2 = 0; d2 < 4; d2++) {
                short8 vf = *reinterpret_cast<const short8*>(Vb8 + kt16 * 4096 + d2 * 1024);
                o[d2] = __builtin_amdgcn_mfma_f32_32x32x16_bf16(pa[kt16], vf, o[d2], 0, 0, 0);
            }
        }
        __builtin_amdgcn_s_setprio(0);
    };

    // ---- peeled iter 0: QK(0) + softmax(0), no PV (needs only K0 landed)
    {
        asm volatile("s_waitcnt vmcnt(12)" ::: "memory");
        __builtin_amdgcn_sched_barrier(0);
        __builtin_amdgcn_s_barrier();
        f32x16 s0, s1;
        qk(0, s0, s1);
        softmax(s0, s1);
        __builtin_amdgcn_sched_barrier(0);
        __builtin_amdgcn_s_barrier();
        stageK(2); stageV(2);
    }
    // ---- main loop: QK(kt); PV(kt-1) || softmax(kt). Need K(kt), V(kt-1) landed.
    for (int kt = 1; kt < NKT; kt++) {
        if (kt < NKT - 1) asm volatile("s_waitcnt vmcnt(12)" ::: "memory");
        else              asm volatile("s_waitcnt vmcnt(0)" ::: "memory");
        __builtin_amdgcn_sched_barrier(0);
        __builtin_amdgcn_s_barrier();
        f32x16 s0, s1;
        qk(kt, s0, s1);
        pv(kt - 1);                        // MFMA, independent of s0/s1
        softmax(s0, s1);                   // VALU, scheduler interleaves into PV shadow
        __builtin_amdgcn_sched_barrier(0);
        __builtin_amdgcn_s_barrier();
        if (kt + 2 < NKT) { stageK(kt + 2); stageV(kt + 2); }
    }
    pv(NKT - 1);                           // final PV (all loads drained at last iter)

    // denominators
    lsum += __shfl_xor(lsum, 32, 64);

    if (!fuse) {
#pragma unroll
        for (int reg = 0; reg < 16; reg++) {
            int crow = (reg & 3) + 8 * (reg >> 2) + 4 * hi;
            float inv = 1.0f / __shfl(lsum, crow, 64);
            size_t rowg = qbase + w * 32 + crow;
#pragma unroll
            for (int d2 = 0; d2 < 4; d2++)
                Xo[rowg * D_ + d2 * 32 + c5] = f2bf(o[d2][reg] * inv);
        }
    } else {
        float part = 0.f;
#pragma unroll
        for (int reg = 0; reg < 16; reg++) {
            int crow = (reg & 3) + 8 * (reg >> 2) + 4 * hi;
            float inv = 1.0f / __shfl(lsum, crow, 64);
            size_t rowg = (size_t)(qt * 128 + w * 32 + crow) * D_;
#pragma unroll
            for (int d2 = 0; d2 < 4; d2++)
                part += (o[d2][reg] * inv) * rw[rowg + d2 * 32 + c5];
        }
#pragma unroll
        for (int off = 32; off > 0; off >>= 1) part += __shfl_xor(part, off, 64);
        if (lane == 0) atomicAdd(out + b, part);
        if (qt == 0 && t == 0) atomicAdd(out + b, rb[0]);
    }
}

// ---------------------------------------------------------------- launch
extern "C" void kernel_launch(void* const* d_in, const int* in_sizes, int n_in,
                              void* d_out, int out_size, void* d_ws, size_t ws_size,
                              hipStream_t stream) {
    const float* genotypes = (const float*)d_in[0];
    const float* emb       = (const float*)d_in[1];
    const float* qw        = (const float*)d_in[2];
    const float* qb        = (const float*)d_in[3];
    const float* kw        = (const float*)d_in[4];
    const float* kb        = (const float*)d_in[5];
    const float* vw        = (const float*)d_in[6];
    const float* vb        = (const float*)d_in[7];
    const float* rw        = (const float*)d_in[8];
    const float* rb        = (const float*)d_in[9];
    float* out = (float*)d_out;

    const size_t NBL = (size_t)B_ * L_;        // 65536
    short* X   = (short*)d_ws;
    short* Qf  = X  + NBL * D_;
    short* Kf  = Qf + NBL * D_;
    short* Vf  = Kf + NBL * D_;
    short* Wbf = Vf + NBL * D_;                // 3 layers x 3 mats x 16384 bf16 (pre-swizzled)

    hipMemsetAsync(out, 0, out_size * sizeof(float), stream);
    k_form_x<<<dim3((NBL * D_ / 8) / 256), 256, 0, stream>>>(genotypes, emb, X);
    k_convw<<<dim3(24, 3), 256, 0, stream>>>(qw, kw, vw, Wbf);
    for (int layer = 0; layer < NL_; layer++) {
        int boff = layer * D_;
        k_qkv3<<<dim3(512), 256, 0, stream>>>(X, Wbf + (size_t)layer * 3 * 16384,
                                              qb + boff, kb + boff, vb + boff,
                                              Qf, Kf, Vf);
        k_attn<<<dim3(512), 256, 0, stream>>>(Qf, Kf, Vf, X, rw, rb, out,
                                              layer == NL_ - 1 ? 1 : 0);
    }
}

// Round 13
// 329.275 us; speedup vs baseline: 1.0628x; 1.0628x over previous
//
#include <hip/hip_runtime.h>
#include <hip/hip_bf16.h>

// Shapes
#define B_   32
#define L_   2048
#define D_   128
#define NL_  3
#define KVB  64
#define NKT  (L_ / KVB)         // 32

typedef __attribute__((ext_vector_type(8))) short short8;
typedef __attribute__((ext_vector_type(4))) float f32x4;
typedef __attribute__((ext_vector_type(16))) float f32x16;

__device__ __forceinline__ short f2bf(float f) {
    unsigned u = __builtin_bit_cast(unsigned, f);
    u += 0x7fffu + ((u >> 16) & 1u);          // RNE
    return (short)(u >> 16);
}
// v_exp_f32 computes 2^x
__device__ __forceinline__ float exp2g(float x) {
    float r; asm("v_exp_f32 %0, %1" : "=v"(r) : "v"(x)); return r;
}
// pack two f32 -> 2x bf16 in one u32 (low=a, high=b), RNE
__device__ __forceinline__ unsigned cvtpk(float a, float b) {
    unsigned r; asm("v_cvt_pk_bf16_f32 %0, %1, %2" : "=v"(r) : "v"(a), "v"(b)); return r;
}
// swap halves across lane<32 / lane>=32 (m214 T12 pattern)
__device__ __forceinline__ void plswap(unsigned& a, unsigned& b) {
    asm volatile("v_permlane32_swap_b32 %0, %1" : "+v"(a), "+v"(b));
}

// async global -> LDS, 16 bytes per lane (dest must be linear: base + lane*16)
__device__ __forceinline__ void gll16(const void* g, void* l) {
    __builtin_amdgcn_global_load_lds(
        (__attribute__((address_space(1))) void*)(g),
        (__attribute__((address_space(3))) void*)(l), 16, 0, 0);
}

// Fragment-order global layouts (16B granule per lane):
//  Q/K: addr = b*512K + blk32*8K + dst*1K + lane*16
//  Vt:  addr = b*512K + kt*16K + k16*4K + d2*1K + lane*16

// ---------------------------------------------------------------- form x
__global__ __launch_bounds__(256) void k_form_x(const float* __restrict__ g,
                                                const float* __restrict__ emb,
                                                short* __restrict__ X) {
    int tid = blockIdx.x * 256 + threadIdx.x;   // one thread = 8 elements
    int bl  = tid >> 4;
    int d8  = (tid & 15) << 3;
    int l   = bl & (L_ - 1);
    float gv = g[bl];
    const float4* e = reinterpret_cast<const float4*>(emb + (size_t)l * D_ + d8);
    float4 a = e[0], b = e[1];
    short8 r;
    r[0]=f2bf(a.x*gv); r[1]=f2bf(a.y*gv); r[2]=f2bf(a.z*gv); r[3]=f2bf(a.w*gv);
    r[4]=f2bf(b.x*gv); r[5]=f2bf(b.y*gv); r[6]=f2bf(b.z*gv); r[7]=f2bf(b.w*gv);
    *reinterpret_cast<short8*>(X + (size_t)tid * 8) = r;
}

// ---------------------------------------------------------------- weight convert
__global__ __launch_bounds__(256) void k_convw(const float* __restrict__ qw,
                                               const float* __restrict__ kw,
                                               const float* __restrict__ vw,
                                               short* __restrict__ Wbf) {
    const float* src = (blockIdx.y == 0) ? qw : (blockIdx.y == 1) ? kw : vw;
    int tid = blockIdx.x * 256 + threadIdx.x;   // 0..6143
    int layer = tid >> 11;
    int i = tid & 2047;
    int Lb = i * 16;
    int row = Lb >> 8, c = (Lb & 255) ^ ((row & 7) << 4);
    const float4* p = reinterpret_cast<const float4*>(src + (size_t)layer * 16384 + row * 128 + (c >> 1));
    float4 a = p[0], b = p[1];
    short8 s;
    s[0]=f2bf(a.x); s[1]=f2bf(a.y); s[2]=f2bf(a.z); s[3]=f2bf(a.w);
    s[4]=f2bf(b.x); s[5]=f2bf(b.y); s[6]=f2bf(b.z); s[7]=f2bf(b.w);
    size_t off = ((size_t)layer * 3 + blockIdx.y) * 16384;
    *reinterpret_cast<short8*>(Wbf + off + (size_t)i * 8) = s;
}

// ---------------------------------------------------------------- fused QKV GEMM
// ONE launch: 512 blocks (XCD-grouped, matches attn's batch<->XCD map).
// X staged once; W (32KB, L2-hot) re-staged per mat between barriers.
// Outputs in FRAGMENT ORDER. Q pre-scaled by log2(e).
__global__ __launch_bounds__(256, 2) void k_qkv3(const short* __restrict__ X,
    const short* __restrict__ Wl,
    const float* __restrict__ bq, const float* __restrict__ bk, const float* __restrict__ bv,
    short* __restrict__ Qf, short* __restrict__ Kf, short* __restrict__ Vf) {
    __shared__ short xs[128 * 128];
    __shared__ short wsh[128 * 128];
    const int t = threadIdx.x;
    int flat = blockIdx.x, xcd = flat & 7, idx = flat >> 3;
    int rblk = xcd * 64 + idx;                 // XCD0 -> rows 0..8191 = batches 0..3
    const size_t rowbase = (size_t)rblk * 128;

    const char* Xg = reinterpret_cast<const char*>(X) + rowbase * 256;
#pragma unroll
    for (int p = 0; p < 8; p++) {
        int Lb = (p * 256 + t) * 16;
        int row = Lb >> 8, c = Lb & 255;
        gll16(Xg + (size_t)row * 256 + (c ^ ((row & 7) << 4)),
              reinterpret_cast<char*>(xs) + Lb);
    }
#pragma unroll
    for (int p = 0; p < 8; p++) {             // W for mat 0
        int Lb = (p * 256 + t) * 16;
        gll16(reinterpret_cast<const char*>(Wl) + Lb,
              reinterpret_cast<char*>(wsh) + Lb);
    }
    __syncthreads();

    const int wave = t >> 6, lane = t & 63, g = lane >> 4, ln = lane & 15;
    const int bb2 = (int)(rowbase >> 11);      // batch
    const int l0  = (int)(rowbase & (L_ - 1)); // row within batch

#pragma unroll
    for (int mat = 0; mat < 3; mat++) {
        if (mat > 0) {
            __syncthreads();                   // all waves done reading wsh (mat-1)
#pragma unroll
            for (int p = 0; p < 8; p++) {
                int Lb = (p * 256 + t) * 16;
                gll16(reinterpret_cast<const char*>(Wl + mat * 16384) + Lb,
                      reinterpret_cast<char*>(wsh) + Lb);
            }
            __syncthreads();                   // vmcnt(0) drained before barrier
        }
        const float* bias = (mat == 0) ? bq : (mat == 1) ? bk : bv;
        f32x4 acc[2][8];
#pragma unroll
        for (int mi = 0; mi < 2; mi++)
#pragma unroll
            for (int ni = 0; ni < 8; ni++) acc[mi][ni] = f32x4{0.f, 0.f, 0.f, 0.f};

        if (mat < 2) {
            // A = W (rows e), B = X (rows l) -> C[e][l]
#pragma unroll
            for (int kk = 0; kk < 4; kk++) {
                short8 aW[2];
#pragma unroll
                for (int mi = 0; mi < 2; mi++) {
                    int row = wave * 32 + mi * 16 + ln;
                    int byte = (row * 256 + kk * 64 + g * 16) ^ ((row & 7) << 4);
                    aW[mi] = *reinterpret_cast<const short8*>(reinterpret_cast<const char*>(wsh) + byte);
                }
#pragma unroll
                for (int ni = 0; ni < 8; ni++) {
                    int row = ni * 16 + ln;
                    int byte = (row * 256 + kk * 64 + g * 16) ^ ((row & 7) << 4);
                    short8 bX = *reinterpret_cast<const short8*>(reinterpret_cast<const char*>(xs) + byte);
                    acc[0][ni] = __builtin_amdgcn_mfma_f32_16x16x32_bf16(aW[0], bX, acc[0][ni], 0, 0, 0);
                    acc[1][ni] = __builtin_amdgcn_mfma_f32_16x16x32_bf16(aW[1], bX, acc[1][ni], 0, 0, 0);
                }
            }
            const float qscale = (mat == 0) ? 1.4426950408889634f : 1.0f;
            char* oc = reinterpret_cast<char*>((mat == 0) ? Qf : Kf) + ((size_t)bb2 << 19);
            int lidx_hi = ((g >> 1) & 1) << 5;
#pragma unroll
            for (int mi = 0; mi < 2; mi++) {
                int e0 = wave * 32 + mi * 16 + g * 4;
                int dst = wave * 2 + mi;
                float4 b4 = *reinterpret_cast<const float4*>(bias + e0);
#pragma unroll
                for (int ni = 0; ni < 8; ni++) {
                    unsigned lo = (unsigned short)f2bf((acc[mi][ni][0] + b4.x) * qscale)
                                | ((unsigned)(unsigned short)f2bf((acc[mi][ni][1] + b4.y) * qscale) << 16);
                    unsigned hi2 = (unsigned short)f2bf((acc[mi][ni][2] + b4.z) * qscale)
                                | ((unsigned)(unsigned short)f2bf((acc[mi][ni][3] + b4.w) * qscale) << 16);
                    int blk32 = (l0 >> 5) + (ni >> 1);
                    int l31 = ((ni & 1) << 4) + ln;
                    size_t off = ((size_t)(blk32 * 8 + dst) << 10)
                               + ((lidx_hi + l31) << 4) + ((g & 1) << 3);
                    int2 pk; pk.x = (int)lo; pk.y = (int)hi2;
                    *reinterpret_cast<int2*>(oc + off) = pk;
                }
            }
        } else {
            // V: A = X (rows l), B = W (rows e) -> C[l][e]
#pragma unroll
            for (int kk = 0; kk < 4; kk++) {
                short8 aX[2];
#pragma unroll
                for (int mi = 0; mi < 2; mi++) {
                    int row = wave * 32 + mi * 16 + ln;
                    int byte = (row * 256 + kk * 64 + g * 16) ^ ((row & 7) << 4);
                    aX[mi] = *reinterpret_cast<const short8*>(reinterpret_cast<const char*>(xs) + byte);
                }
#pragma unroll
                for (int ni = 0; ni < 8; ni++) {
                    int row = ni * 16 + ln;
                    int byte = (row * 256 + kk * 64 + g * 16) ^ ((row & 7) << 4);
                    short8 bW = *reinterpret_cast<const short8*>(reinterpret_cast<const char*>(wsh) + byte);
                    acc[0][ni] = __builtin_amdgcn_mfma_f32_16x16x32_bf16(aX[0], bW, acc[0][ni], 0, 0, 0);
                    acc[1][ni] = __builtin_amdgcn_mfma_f32_16x16x32_bf16(aX[1], bW, acc[1][ni], 0, 0, 0);
                }
            }
            char* oc = reinterpret_cast<char*>(Vf) + ((size_t)bb2 << 19);
#pragma unroll
            for (int ni = 0; ni < 8; ni++) {
                int d = ni * 16 + ln;
                float bvv = bias[d];
                int d2 = d >> 5, d31 = d & 31;
#pragma unroll
                for (int mi = 0; mi < 2; mi++) {
                    unsigned lo = (unsigned short)f2bf(acc[mi][ni][0] + bvv)
                                | ((unsigned)(unsigned short)f2bf(acc[mi][ni][1] + bvv) << 16);
                    unsigned hi2 = (unsigned short)f2bf(acc[mi][ni][2] + bvv)
                                | ((unsigned)(unsigned short)f2bf(acc[mi][ni][3] + bvv) << 16);
                    int lglob = l0 + wave * 32 + mi * 16 + g * 4;
                    int kt = lglob >> 6, k16 = (lglob >> 4) & 3, lhi = (lglob >> 3) & 1;
                    size_t off = ((size_t)kt << 14) + (k16 << 12) + (d2 << 10)
                               + ((lhi * 32 + d31) << 4) + ((g & 1) << 3);
                    int2 pk; pk.x = (int)lo; pk.y = (int)hi2;
                    *reinterpret_cast<int2*>(oc + off) = pk;
                }
            }
        }
    }
}

// ---------------------------------------------------------------- flash attention
// R11 structure (confirmed best) + safe micros only: T15 pipeline
// (QK(t) -> PV(t-1) || softmax(t)); V triple-buffered, K double-buffered,
// K-before-V issue queue, vmcnt(12). Micros: z16-seeded single QK chains
// (no per-iter zero-movs, NO chain split), tree-reduced lsum.
__global__ __launch_bounds__(256, 2) void k_attn(const short* __restrict__ Qf,
                                                 const short* __restrict__ Kf,
                                                 const short* __restrict__ Vf,
                                                 short* __restrict__ Xo,
                                                 const float* __restrict__ rw,
                                                 const float* __restrict__ rb,
                                                 float* __restrict__ out,
                                                 int fuse) {
    __shared__ short Ks[2][KVB * 128];    // 2 x 16 KB, fragment order
    __shared__ short Vts[3][128 * KVB];   // 3 x 16 KB, fragment order
    const int t = threadIdx.x, w = t >> 6, lane = t & 63;
    const int hi = lane >> 5, c5 = lane & 31;
    int flat = blockIdx.x;
    int xcd = flat & 7, idx = flat >> 3;
    int b = xcd * 4 + (idx >> 4), qt = idx & 15;
    const size_t qbase = (size_t)b * L_ + qt * 128;

    // Q fragments -> registers (contiguous 1KB per load)
    const char* Qg = reinterpret_cast<const char*>(Qf) + ((size_t)b << 19);
    short8 qf[8];
#pragma unroll
    for (int dst = 0; dst < 8; dst++)
        qf[dst] = *reinterpret_cast<const short8*>(
            Qg + (((size_t)(qt * 4 + w) * 8 + dst) << 10) + lane * 16);
    __builtin_amdgcn_sched_barrier(0);    // pin Q loads before staging (vmcnt accounting)

    const char* Kg = reinterpret_cast<const char*>(Kf) + ((size_t)b << 19);
    const char* Vg = reinterpret_cast<const char*>(Vf) + ((size_t)b << 19);

    auto stageK = [&](int kt) {
#pragma unroll
        for (int p = 0; p < 4; p++) {
            int Lb = (p * 256 + t) * 16;
            gll16(Kg + ((size_t)kt << 14) + Lb, reinterpret_cast<char*>(Ks[kt & 1]) + Lb);
        }
    };
    auto stageV = [&](int kt) {
#pragma unroll
        for (int p = 0; p < 4; p++) {
            int Lb = (p * 256 + t) * 16;
            gll16(Vg + ((size_t)kt << 14) + Lb, reinterpret_cast<char*>(Vts[kt % 3]) + Lb);
        }
    };

    // issue queue: K0 K1 V0 V1 | K2 V2 | K3 V3 | ...  (K-before-V prefix property)
    stageK(0); stageK(1); stageV(0); stageV(1);

    f32x16 z16;                           // hoisted zero C-operand (loop-invariant)
#pragma unroll
    for (int r = 0; r < 16; r++) z16[r] = 0.f;

    f32x16 o[4];
#pragma unroll
    for (int d2 = 0; d2 < 4; d2++) o[d2] = z16;
    float lsum = 0.f;
    short8 pa[4];                         // P fragments of the PREVIOUS iter

    auto softmax = [&](const f32x16& s0, const f32x16& s1) {
        float e0[16], e1[16];
#pragma unroll
        for (int r = 0; r < 16; r++) { e0[r] = exp2g(s0[r]); e1[r] = exp2g(s1[r]); }
        // tree-reduce: 16 independent adds, then depth-4 tree (chain depth ~6)
        float tr[16];
#pragma unroll
        for (int r = 0; r < 16; r++) tr[r] = e0[r] + e1[r];
#pragma unroll
        for (int st = 8; st > 0; st >>= 1)
#pragma unroll
            for (int r = 0; r < st; r++) tr[r] += tr[r + st];
        lsum += tr[0];
#pragma unroll
        for (int kt16 = 0; kt16 < 4; kt16++) {
            const float* e = (kt16 < 2) ? e0 : e1;
            int rb2 = (kt16 & 1) * 8;
            unsigned w01 = cvtpk(e[rb2 + 0], e[rb2 + 1]);
            unsigned w23 = cvtpk(e[rb2 + 2], e[rb2 + 3]);
            unsigned w45 = cvtpk(e[rb2 + 4], e[rb2 + 5]);
            unsigned w67 = cvtpk(e[rb2 + 6], e[rb2 + 7]);
            plswap(w01, w45);
            plswap(w23, w67);
            uint4 fr; fr.x = w01; fr.y = w23; fr.z = w45; fr.w = w67;
            pa[kt16] = __builtin_bit_cast(short8, fr);
        }
    };
    auto qk = [&](int kt, f32x16& s0, f32x16& s1) {
        const char* Kb8 = reinterpret_cast<const char*>(Ks[kt & 1]) + lane * 16;
        __builtin_amdgcn_s_setprio(1);
        // two 8-deep chains (HW forwards accumulator), seeded with hoisted z16
        {
            short8 k0 = *reinterpret_cast<const short8*>(Kb8);
            short8 k1 = *reinterpret_cast<const short8*>(Kb8 + 8192);
            s0 = __builtin_amdgcn_mfma_f32_32x32x16_bf16(k0, qf[0], z16, 0, 0, 0);
            s1 = __builtin_amdgcn_mfma_f32_32x32x16_bf16(k1, qf[0], z16, 0, 0, 0);
        }
#pragma unroll
        for (int dst = 1; dst < 8; dst++) {
            short8 k0 = *reinterpret_cast<const short8*>(Kb8 + dst * 1024);
            short8 k1 = *reinterpret_cast<const short8*>(Kb8 + 8192 + dst * 1024);
            s0 = __builtin_amdgcn_mfma_f32_32x32x16_bf16(k0, qf[dst], s0, 0, 0, 0);
            s1 = __builtin_amdgcn_mfma_f32_32x32x16_bf16(k1, qf[dst], s1, 0, 0, 0);
        }
        __builtin_amdgcn_s_setprio(0);
    };
    auto pv = [&](int kt) {               // O += P(kt).V(kt), pa holds P(kt)
        const char* Vb8 = reinterpret_cast<const char*>(Vts[kt % 3]) + lane * 16;
        __builtin_amdgcn_s_setprio(1);
#pragma unroll
        for (int kt16 = 0; kt16 < 4; kt16++) {
#pragma unroll
            for (int d2 = 0; d2 < 4; d2++) {
                short8 vf = *reinterpret_cast<const short8*>(Vb8 + kt16 * 4096 + d2 * 1024);
                o[d2] = __builtin_amdgcn_mfma_f32_32x32x16_bf16(pa[kt16], vf, o[d2], 0, 0, 0);
            }
        }
        __builtin_amdgcn_s_setprio(0);
    };

    // ---- peeled iter 0: QK(0) + softmax(0), no PV (needs only K0 landed)
    {
        asm volatile("s_waitcnt vmcnt(12)" ::: "memory");
        __builtin_amdgcn_sched_barrier(0);
        __builtin_amdgcn_s_barrier();
        f32x16 s0, s1;
        qk(0, s0, s1);
        softmax(s0, s1);
        __builtin_amdgcn_sched_barrier(0);
        __builtin_amdgcn_s_barrier();
        stageK(2); stageV(2);
    }
    // ---- main loop: QK(kt); PV(kt-1) || softmax(kt). Need K(kt), V(kt-1) landed.
    for (int kt = 1; kt < NKT; kt++) {
        if (kt < NKT - 1) asm volatile("s_waitcnt vmcnt(12)" ::: "memory");
        else              asm volatile("s_waitcnt vmcnt(0)" ::: "memory");
        __builtin_amdgcn_sched_barrier(0);
        __builtin_amdgcn_s_barrier();
        f32x16 s0, s1;
        qk(kt, s0, s1);
        pv(kt - 1);                        // MFMA, independent of s0/s1
        softmax(s0, s1);                   // VALU, scheduler interleaves into PV shadow
        __builtin_amdgcn_sched_barrier(0);
        __builtin_amdgcn_s_barrier();
        if (kt + 2 < NKT) { stageK(kt + 2); stageV(kt + 2); }
    }
    pv(NKT - 1);                           // final PV (all loads drained at last iter)

    // denominators
    lsum += __shfl_xor(lsum, 32, 64);

    if (!fuse) {
#pragma unroll
        for (int reg = 0; reg < 16; reg++) {
            int crow = (reg & 3) + 8 * (reg >> 2) + 4 * hi;
            float inv = 1.0f / __shfl(lsum, crow, 64);
            size_t rowg = qbase + w * 32 + crow;
#pragma unroll
            for (int d2 = 0; d2 < 4; d2++)
                Xo[rowg * D_ + d2 * 32 + c5] = f2bf(o[d2][reg] * inv);
        }
    } else {
        float part = 0.f;
#pragma unroll
        for (int reg = 0; reg < 16; reg++) {
            int crow = (reg & 3) + 8 * (reg >> 2) + 4 * hi;
            float inv = 1.0f / __shfl(lsum, crow, 64);
            size_t rowg = (size_t)(qt * 128 + w * 32 + crow) * D_;
#pragma unroll
            for (int d2 = 0; d2 < 4; d2++)
                part += (o[d2][reg] * inv) * rw[rowg + d2 * 32 + c5];
        }
#pragma unroll
        for (int off = 32; off > 0; off >>= 1) part += __shfl_xor(part, off, 64);
        if (lane == 0) atomicAdd(out + b, part);
        if (qt == 0 && t == 0) atomicAdd(out + b, rb[0]);
    }
}

// ---------------------------------------------------------------- launch
extern "C" void kernel_launch(void* const* d_in, const int* in_sizes, int n_in,
                              void* d_out, int out_size, void* d_ws, size_t ws_size,
                              hipStream_t stream) {
    const float* genotypes = (const float*)d_in[0];
    const float* emb       = (const float*)d_in[1];
    const float* qw        = (const float*)d_in[2];
    const float* qb        = (const float*)d_in[3];
    const float* kw        = (const float*)d_in[4];
    const float* kb        = (const float*)d_in[5];
    const float* vw        = (const float*)d_in[6];
    const float* vb        = (const float*)d_in[7];
    const float* rw        = (const float*)d_in[8];
    const float* rb        = (const float*)d_in[9];
    float* out = (float*)d_out;

    const size_t NBL = (size_t)B_ * L_;        // 65536
    short* X   = (short*)d_ws;
    short* Qf  = X  + NBL * D_;
    short* Kf  = Qf + NBL * D_;
    short* Vf  = Kf + NBL * D_;
    short* Wbf = Vf + NBL * D_;                // 3 layers x 3 mats x 16384 bf16 (pre-swizzled)

    hipMemsetAsync(out, 0, out_size * sizeof(float), stream);
    k_form_x<<<dim3((NBL * D_ / 8) / 256), 256, 0, stream>>>(genotypes, emb, X);
    k_convw<<<dim3(24, 3), 256, 0, stream>>>(qw, kw, vw, Wbf);
    for (int layer = 0; layer < NL_; layer++) {
        int boff = layer * D_;
        k_qkv3<<<dim3(512), 256, 0, stream>>>(X, Wbf + (size_t)layer * 3 * 16384,
                                              qb + boff, kb + boff, vb + boff,
                                              Qf, Kf, Vf);
        k_attn<<<dim3(512), 256, 0, stream>>>(Qf, Kf, Vf, X, rw, rb, out,
                                              layer == NL_ - 1 ? 1 : 0);
    }
}